// Round 6
// baseline (51.721 us; speedup 1.0000x reference)
//
#include <hip/hip_runtime.h>
#include <math.h>

#define PI_HALF 1.57079632679489662f

typedef float v2f __attribute__((ext_vector_type(2)));
typedef unsigned uv2 __attribute__((ext_vector_type(2)));

// ---------------------------------------------------------------------------
// R6 layout: 2 samples / wave, 32 lanes / sample, 8 complex amps / lane.
// Amplitude index i (0..255): bits [7:3] = g (lane&31) -> qubits 0..4
//                             bits [2:0] = (j1,j0,h)   -> qubits 5,6,7
// State: v2f RE[4], IM[4];  RE[j] = (re[i], re[i+1]) with h packed in v2f.
// Qubit w -> g bit (4-w) for w<=4 (lane exchange: DPP masks 8/4/2/1,
// permlane16_swap for mask 16), qubit 5 -> j bit1, 6 -> j bit0, 7 -> h.
// Rationale: 4 samples/wave caps total waves at 4096 (50% of the chip's 8192
// wave slots; measured occupancy 28%, VALUBusy 56%). Halving amps/lane
// doubles TLP to hide the DPP+FMA latency chains.
// ---------------------------------------------------------------------------

__device__ __forceinline__ v2f sp(float x) { v2f r; r.x = x; r.y = x; return r; }
__device__ __forceinline__ v2f pkfma(v2f a, v2f b, v2f c) {
  return __builtin_elementwise_fma(a, b, c);
}

template <int CTRL>
__device__ __forceinline__ float dpp_mov(float v) {
  int r = __builtin_amdgcn_update_dpp(0, __float_as_int(v), CTRL, 0xf, 0xf, true);
  return __int_as_float(r);
}

// xor of lane bits within a sample's 32 lanes. MASK in {1,2,4,8,16}.
template <int MASK>
__device__ __forceinline__ float lane_xor(float v, bool odd) {
  if constexpr (MASK == 1) return dpp_mov<0xB1>(v);        // quad_perm [1,0,3,2]
  else if constexpr (MASK == 2) return dpp_mov<0x4E>(v);   // quad_perm [2,3,0,1]
  else if constexpr (MASK == 4) return dpp_mov<0x1B>(dpp_mov<0x141>(v));
  else if constexpr (MASK == 8) return dpp_mov<0x128>(v);  // row_ror:8
  else {
#if __has_builtin(__builtin_amdgcn_permlane16_swap)
    // swap(x,x): r.x = {x.r0,x.r0,x.r2,x.r2}, r.y = {x.r1,x.r1,x.r3,x.r3}
    uv2 r = __builtin_amdgcn_permlane16_swap(__float_as_uint(v),
                                             __float_as_uint(v), false, false);
    return __uint_as_float(odd ? r.x : r.y);
#else
    return __int_as_float(__builtin_amdgcn_ds_swizzle(__float_as_int(v), 0x401F));
#endif
  }
}
template <int MASK>
__device__ __forceinline__ v2f dpp2(v2f v, bool odd) {
  v2f r; r.x = lane_xor<MASK>(v.x, odd); r.y = lane_xor<MASK>(v.y, odd);
  return r;
}

// --- Rot gates. mA = (m00r, m00i, m01r, m01i); m11=conj(m00), m10=-conj(m01)
template <int W>  // lane qubit, W in 0..4, mask = 1<<(4-W)
__device__ __forceinline__ void rot_lane(v2f (&RE)[4], v2f (&IM)[4],
                                         const float4 mA, int g) {
  constexpr int LM = 1 << (4 - W);
  const bool odd = (g >> 4) & 1;
  const unsigned bit = (g >> (4 - W)) & 1u;
  const int sgn = (int)(bit << 31);
  v2f Av = sp(mA.x);
  v2f Bv = sp(__int_as_float(__float_as_int(mA.y) ^ sgn));
  v2f Cv = sp(__int_as_float(__float_as_int(mA.z) ^ sgn));
  v2f Dv = sp(mA.w);
#pragma unroll
  for (int j = 0; j < 4; ++j) {
    v2f pr = dpp2<LM>(RE[j], odd);
    v2f pi = dpp2<LM>(IM[j], odd);
    v2f nr = pkfma(-Dv, pi, pkfma(Cv, pr, pkfma(-Bv, IM[j], Av * RE[j])));
    v2f ni = pkfma( Dv, pr, pkfma(Cv, pi, pkfma( Bv, RE[j], Av * IM[j])));
    RE[j] = nr; IM[j] = ni;
  }
}

template <int JM>  // reg qubit via j-bit: q5 JM=2, q6 JM=1
__device__ __forceinline__ void rot_regj(v2f (&RE)[4], v2f (&IM)[4],
                                         const float4 mA) {
  v2f M0r = sp(mA.x), M0i = sp(mA.y), M1r = sp(mA.z), M1i = sp(mA.w);
#pragma unroll
  for (int j = 0; j < 4; ++j) {
    if (!(j & JM)) {
      const int j1 = j | JM;
      v2f r0 = RE[j], i0 = IM[j], r1 = RE[j1], i1 = IM[j1];
      RE[j]  = pkfma(-M1i, i1, pkfma(M1r, r1, pkfma(-M0i, i0, M0r * r0)));
      IM[j]  = pkfma( M1i, r1, pkfma(M1r, i1, pkfma( M0i, r0, M0r * i0)));
      RE[j1] = pkfma( M0i, i1, pkfma(M0r, r1, pkfma(-M1i, i0, (-M1r) * r0)));
      IM[j1] = pkfma(-M0i, r1, pkfma(M0r, i1, pkfma( M1i, r0, (-M1r) * i0)));
    }
  }
}

__device__ __forceinline__ void rot_regh(v2f (&RE)[4], v2f (&IM)[4],
                                         const float4 mA) {  // q7 (h bit)
#pragma unroll
  for (int j = 0; j < 4; ++j) {
    float r0 = RE[j].x, i0 = IM[j].x, r1 = RE[j].y, i1 = IM[j].y;
    RE[j].x = fmaf(-mA.w, i1, fmaf(mA.z, r1, fmaf(-mA.y, i0, mA.x * r0)));
    IM[j].x = fmaf( mA.w, r1, fmaf(mA.z, i1, fmaf( mA.y, r0, mA.x * i0)));
    RE[j].y = fmaf( mA.y, i1, fmaf(mA.x, r1, fmaf(-mA.w, i0, -mA.z * r0)));
    IM[j].y = fmaf(-mA.y, r1, fmaf(mA.x, i1, fmaf( mA.w, r0, -mA.z * i0)));
  }
}

// --- CNOTs. new[i] = bitC(i) ? old[i ^ maskT] : old[i]
template <int GPOS, int LM>  // C lane (g bit GPOS), T lane (xor LM)
__device__ __forceinline__ void cnot_LL(v2f (&RE)[4], v2f (&IM)[4], int g) {
  const bool cb = (g >> GPOS) & 1;
  const bool odd = (g >> 4) & 1;
#pragma unroll
  for (int j = 0; j < 4; ++j) {
    v2f pr = dpp2<LM>(RE[j], odd);
    v2f pi = dpp2<LM>(IM[j], odd);
    RE[j] = cb ? pr : RE[j];
    IM[j] = cb ? pi : IM[j];
  }
}
template <int GPOS, int JM>  // C lane, T reg j-bit
__device__ __forceinline__ void cnot_LR(v2f (&RE)[4], v2f (&IM)[4], int g) {
  const bool cb = (g >> GPOS) & 1;
#pragma unroll
  for (int j = 0; j < 4; ++j) {
    if (!(j & JM)) {
      const int j1 = j | JM;
      v2f r0 = RE[j], r1 = RE[j1];
      RE[j] = cb ? r1 : r0;  RE[j1] = cb ? r0 : r1;
      v2f i0 = IM[j], i1 = IM[j1];
      IM[j] = cb ? i1 : i0;  IM[j1] = cb ? i0 : i1;
    }
  }
}
template <int GPOS>  // C lane, T h
__device__ __forceinline__ void cnot_LH(v2f (&RE)[4], v2f (&IM)[4], int g) {
  const bool cb = (g >> GPOS) & 1;
#pragma unroll
  for (int j = 0; j < 4; ++j) {
    v2f r = RE[j]; v2f rs; rs.x = r.y; rs.y = r.x;
    RE[j] = cb ? rs : r;
    v2f i = IM[j]; v2f is2; is2.x = i.y; is2.y = i.x;
    IM[j] = cb ? is2 : i;
  }
}
template <int JC, int LM>  // C reg j-bit, T lane
__device__ __forceinline__ void cnot_RL(v2f (&RE)[4], v2f (&IM)[4], int g) {
  const bool odd = (g >> 4) & 1;
#pragma unroll
  for (int j = 0; j < 4; ++j) {
    if (j & JC) {
      RE[j] = dpp2<LM>(RE[j], odd);
      IM[j] = dpp2<LM>(IM[j], odd);
    }
  }
}
template <int JC>  // C reg j-bit, T h
__device__ __forceinline__ void cnot_RH(v2f (&RE)[4], v2f (&IM)[4]) {
#pragma unroll
  for (int j = 0; j < 4; ++j) {
    if (j & JC) {
      v2f r = RE[j]; RE[j].x = r.y; RE[j].y = r.x;
      v2f i = IM[j]; IM[j].x = i.y; IM[j].y = i.x;
    }
  }
}
template <int LM>  // C h, T lane (h=1 components move)
__device__ __forceinline__ void cnot_HL(v2f (&RE)[4], v2f (&IM)[4], int g) {
  const bool odd = (g >> 4) & 1;
#pragma unroll
  for (int j = 0; j < 4; ++j) {
    RE[j].y = lane_xor<LM>(RE[j].y, odd);
    IM[j].y = lane_xor<LM>(IM[j].y, odd);
  }
}
template <int JC, int JT>  // C reg, T reg: static swaps
__device__ __forceinline__ void cnot_RR(v2f (&RE)[4], v2f (&IM)[4]) {
#pragma unroll
  for (int j = 0; j < 4; ++j) {
    if ((j & JC) && !(j & JT)) {
      const int j1 = j | JT;
      v2f t = RE[j]; RE[j] = RE[j1]; RE[j1] = t;
      t = IM[j]; IM[j] = IM[j1]; IM[j1] = t;
    }
  }
}

__device__ __forceinline__ void stage_fence() { __threadfence_block(); }

__global__ __launch_bounds__(256) void hqc_kernel(
    const float* __restrict__ x,
    const float* __restrict__ w1, const float* __restrict__ b1,
    const float* __restrict__ w2, const float* __restrict__ b2,
    const float* __restrict__ w3, const float* __restrict__ b3,
    const float* __restrict__ qw,
    const float* __restrict__ wp1, const float* __restrict__ bp1,
    const float* __restrict__ wp2, const float* __restrict__ bp2,
    const float* __restrict__ wp3, const float* __restrict__ bp3,
    float* __restrict__ out, int B) {
  __shared__ __align__(16) float rotm[32][4];  // m00r,m00i,m01r,m01i per gate
  __shared__ float xbuf[8][44];
  __shared__ __align__(16) float hbuf[8][68];
  __shared__ float h2buf[8][34];
  __shared__ float qbuf[8][20];
  __shared__ float p1buf[8][34];
  __shared__ float p2buf[8][20];

  const int tid = threadIdx.x;
  const int g = tid & 31;   // lane within 32-lane sample group
  const int ls = tid >> 5;  // sample slot in block (0..7)
  const int s = blockIdx.x * 8 + ls;
  const bool valid = (s < B);

  // --- Rot coefficient setup: one thread per gate ---
  if (tid < 32) {
    float phi = qw[tid * 3 + 0];
    float th  = qw[tid * 3 + 1];
    float om  = qw[tid * 3 + 2];
    float st_, ct; sincosf(0.5f * th, &st_, &ct);
    float sa, ca;  sincosf(0.5f * (phi + om), &sa, &ca);
    float sb, cb;  sincosf(0.5f * (phi - om), &sb, &cb);
    rotm[tid][0] =  ca * ct;   // m00r
    rotm[tid][1] = -sa * ct;   // m00i
    rotm[tid][2] = -cb * st_;  // m01r
    rotm[tid][3] = -sb * st_;  // m01i
  }

  if (valid) {
    xbuf[ls][g] = x[s * 41 + g];
    if (g < 9) xbuf[ls][g + 32] = x[s * 41 + g + 32];
  }
  __syncthreads();

  // --- pre-MLP layer1: 41 -> 64, lane computes 2 cols (packed) ---
  const v2f* w1v = (const v2f*)w1;  // [41][32]
  v2f a1 = ((const v2f*)b1)[g];
#pragma unroll 8
  for (int k = 0; k < 41; ++k)
    a1 = pkfma(sp(xbuf[ls][k]), w1v[k * 32 + g], a1);
  v2f st2; st2.x = fmaxf(a1.x, 0.f); st2.y = fmaxf(a1.y, 0.f);
  *(v2f*)(&hbuf[ls][2 * g]) = st2;
  stage_fence();

  // --- layer2: 64 -> 32, lane computes 1 col ---
  float a2 = b2[g];
#pragma unroll 8
  for (int k = 0; k < 64; ++k) a2 = fmaf(hbuf[ls][k], w2[k * 32 + g], a2);
  h2buf[ls][g] = fmaxf(a2, 0.f);
  stage_fence();

  // --- layer3: 32 -> 8, tanh, RY encoding ---
  if (g < 8) {
    float acc = b3[g];
#pragma unroll
    for (int k = 0; k < 32; ++k) acc = fmaf(h2buf[ls][k], w3[k * 8 + g], acc);
    float q = tanhf(acc);
    float sh, ch; sincosf(q * PI_HALF, &sh, &ch);
    qbuf[ls][g]     = ch;
    qbuf[ls][8 + g] = sh;
  }
  stage_fence();

  // --- init statevector ---
  float cwv[8], swv[8];
#pragma unroll
  for (int w = 0; w < 8; ++w) { cwv[w] = qbuf[ls][w]; swv[w] = qbuf[ls][8 + w]; }
  float lp = 1.0f;
#pragma unroll
  for (int w = 0; w < 5; ++w) lp *= ((g >> (4 - w)) & 1) ? swv[w] : cwv[w];
  float f56[4];
#pragma unroll
  for (int a = 0; a < 4; ++a)
    f56[a] = ((a & 2) ? swv[5] : cwv[5]) * ((a & 1) ? swv[6] : cwv[6]);
  v2f F7; F7.x = cwv[7]; F7.y = swv[7];
  v2f RE[4], IM[4];
#pragma unroll
  for (int j = 0; j < 4; ++j) {
    RE[j] = sp(lp * f56[j]) * F7;
    IM[j] = sp(0.0f);
  }

#define RM(L, W) (*(const float4*)(&rotm[(L) * 8 + (W)][0]))
#define ROTS(L)                          \
  rot_lane<0>(RE, IM, RM(L, 0), g);      \
  rot_lane<1>(RE, IM, RM(L, 1), g);      \
  rot_lane<2>(RE, IM, RM(L, 2), g);      \
  rot_lane<3>(RE, IM, RM(L, 3), g);      \
  rot_lane<4>(RE, IM, RM(L, 4), g);      \
  rot_regj<2>(RE, IM, RM(L, 5));         \
  rot_regj<1>(RE, IM, RM(L, 6));         \
  rot_regh(RE, IM, RM(L, 7));

  // layer 0, r=1: (0,1)(1,2)(2,3)(3,4)(4,5)(5,6)(6,7)(7,0)
  ROTS(0)
  cnot_LL<4, 8>(RE, IM, g);  cnot_LL<3, 4>(RE, IM, g);
  cnot_LL<2, 2>(RE, IM, g);  cnot_LL<1, 1>(RE, IM, g);
  cnot_LR<0, 2>(RE, IM, g);  cnot_RR<2, 1>(RE, IM);
  cnot_RH<1>(RE, IM);        cnot_HL<16>(RE, IM, g);
  // layer 1, r=2: (0,2)(1,3)(2,4)(3,5)(4,6)(5,7)(6,0)(7,1)
  ROTS(1)
  cnot_LL<4, 4>(RE, IM, g);  cnot_LL<3, 2>(RE, IM, g);
  cnot_LL<2, 1>(RE, IM, g);  cnot_LR<1, 2>(RE, IM, g);
  cnot_LR<0, 1>(RE, IM, g);  cnot_RH<2>(RE, IM);
  cnot_RL<1, 16>(RE, IM, g); cnot_HL<8>(RE, IM, g);
  // layer 2, r=3: (0,3)(1,4)(2,5)(3,6)(4,7)(5,0)(6,1)(7,2)
  ROTS(2)
  cnot_LL<4, 2>(RE, IM, g);  cnot_LL<3, 1>(RE, IM, g);
  cnot_LR<2, 2>(RE, IM, g);  cnot_LR<1, 1>(RE, IM, g);
  cnot_LH<0>(RE, IM, g);     cnot_RL<2, 16>(RE, IM, g);
  cnot_RL<1, 8>(RE, IM, g);  cnot_HL<4>(RE, IM, g);
  // layer 3, r=4: (0,4)(1,5)(2,6)(3,7)(4,0)(5,1)(6,2)(7,3)
  ROTS(3)
  cnot_LL<4, 1>(RE, IM, g);  cnot_LR<3, 2>(RE, IM, g);
  cnot_LR<2, 1>(RE, IM, g);  cnot_LH<1>(RE, IM, g);
  cnot_LL<0, 16>(RE, IM, g); cnot_RL<2, 8>(RE, IM, g);
  cnot_RL<1, 4>(RE, IM, g);  cnot_HL<2>(RE, IM, g);

  // --- expectations ---
  v2f pv[4];
#pragma unroll
  for (int j = 0; j < 4; ++j) pv[j] = pkfma(RE[j], RE[j], IM[j] * IM[j]);
  v2f tv = (pv[0] + pv[1]) + (pv[2] + pv[3]);
  float tot = tv.x + tv.y;
  v2f v5 = pv[2] + pv[3]; float s5 = v5.x + v5.y;  // q5: j bit1
  v2f v6 = pv[1] + pv[3]; float s6 = v6.x + v6.y;  // q6: j bit0
  float s7 = tv.y;                                  // q7: h
  float zp[8];
  zp[0] = ((g >> 4) & 1) ? -tot : tot;
  zp[1] = ((g >> 3) & 1) ? -tot : tot;
  zp[2] = ((g >> 2) & 1) ? -tot : tot;
  zp[3] = ((g >> 1) & 1) ? -tot : tot;
  zp[4] = (g & 1) ? -tot : tot;
  zp[5] = fmaf(-2.f, s5, tot);
  zp[6] = fmaf(-2.f, s6, tot);
  zp[7] = fmaf(-2.f, s7, tot);
  {
    const bool odd = (g >> 4) & 1;
#pragma unroll
    for (int w = 0; w < 8; ++w) zp[w] += lane_xor<1>(zp[w], odd);
#pragma unroll
    for (int w = 0; w < 8; ++w) zp[w] += lane_xor<2>(zp[w], odd);
#pragma unroll
    for (int w = 0; w < 8; ++w) zp[w] += lane_xor<4>(zp[w], odd);
#pragma unroll
    for (int w = 0; w < 8; ++w) zp[w] += lane_xor<8>(zp[w], odd);
#pragma unroll
    for (int w = 0; w < 8; ++w) zp[w] += lane_xor<16>(zp[w], odd);
  }

  // --- post-MLP layer1: 8 -> 32, lane computes 1 col (zp all in regs) ---
  float q1 = bp1[g];
#pragma unroll
  for (int k = 0; k < 8; ++k) q1 = fmaf(zp[k], wp1[k * 32 + g], q1);
  p1buf[ls][g] = fmaxf(q1, 0.f);
  stage_fence();

  // --- post layer2: 32 -> 16 ---
  if (g < 16) {
    float q2 = bp2[g];
#pragma unroll
    for (int k = 0; k < 32; ++k) q2 = fmaf(p1buf[ls][k], wp2[k * 16 + g], q2);
    p2buf[ls][g] = fmaxf(q2, 0.f);
  }
  stage_fence();

  // --- post layer3: 16 -> 5 ---
  if (g < 5 && valid) {
    float o = bp3[g];
#pragma unroll
    for (int k = 0; k < 16; ++k) o = fmaf(p2buf[ls][k], wp3[k * 5 + g], o);
    out[s * 5 + g] = o;
  }
}

extern "C" void kernel_launch(void* const* d_in, const int* in_sizes, int n_in,
                              void* d_out, int out_size, void* d_ws,
                              size_t ws_size, hipStream_t stream) {
  const float* x   = (const float*)d_in[0];
  const float* w1  = (const float*)d_in[1];
  const float* b1  = (const float*)d_in[2];
  const float* w2  = (const float*)d_in[3];
  const float* b2  = (const float*)d_in[4];
  const float* w3  = (const float*)d_in[5];
  const float* b3  = (const float*)d_in[6];
  const float* qw  = (const float*)d_in[7];
  const float* wp1 = (const float*)d_in[8];
  const float* bp1 = (const float*)d_in[9];
  const float* wp2 = (const float*)d_in[10];
  const float* bp2 = (const float*)d_in[11];
  const float* wp3 = (const float*)d_in[12];
  const float* bp3 = (const float*)d_in[13];
  float* out = (float*)d_out;
  const int B = in_sizes[0] / 41;
  const int blocks = (B + 7) / 8;
  hipLaunchKernelGGL(hqc_kernel, dim3(blocks), dim3(256), 0, stream,
                     x, w1, b1, w2, b2, w3, b3, qw,
                     wp1, bp1, wp2, bp2, wp3, bp3, out, B);
}

// Round 7
// 42.681 us; speedup vs baseline: 1.2118x; 1.2118x over previous
//
#include <hip/hip_runtime.h>
#include <math.h>

#define PI_HALF 1.57079632679489662f

typedef float v2f __attribute__((ext_vector_type(2)));

// ---------------------------------------------------------------------------
// R7 = R5 layout (best: 48.7us) + masked-DPP CNOTs + register-prefetched
// rot coefficients + launch_bounds(256,2) for ILP headroom.
//
// Layout: 4 samples / wave, 16 lanes / sample (one DPP row per sample).
// Amplitude index i (0..255): bits [7:4] = g (lane&15) -> qubits 0..3
//                             bits [3:0] = k           -> qubits 4..7
// k = 2*j + h: state v2f RE[8], IM[8]; RE[j] = (re[2j], re[2j+1]).
//   qubit 4 -> j bit2, qubit 5 -> j bit1, qubit 6 -> j bit0, qubit 7 -> h.
// Lane-qubit w (0..3) lives at lane bit (3-w):
//   bit3/bit2 are DPP bank-selectable (bank_mask 0xC / 0xA);
//   bits 1,0 are inside a quad -> conditional swaps encode as quad_perm.
// ---------------------------------------------------------------------------

__device__ __forceinline__ v2f sp(float x) { v2f r; r.x = x; r.y = x; return r; }
__device__ __forceinline__ v2f pkfma(v2f a, v2f b, v2f c) {
  return __builtin_elementwise_fma(a, b, c);
}

template <int CTRL>
__device__ __forceinline__ float dpp_mov(float v) {
  int r = __builtin_amdgcn_update_dpp(0, __float_as_int(v), CTRL, 0xf, 0xf, true);
  return __int_as_float(r);
}
// Masked DPP: lanes outside BANK keep old value (the conditional part of CNOT)
template <int CTRL, int BANK>
__device__ __forceinline__ float mdpp(float old_, float src) {
  int r = __builtin_amdgcn_update_dpp(__float_as_int(old_), __float_as_int(src),
                                      CTRL, 0xf, BANK, false);
  return __int_as_float(r);
}

template <int MASK>  // xor within 16-lane rows, MASK in {1,2,4,8}
__device__ __forceinline__ float lane_xor(float v) {
  if constexpr (MASK == 1) return dpp_mov<0xB1>(v);        // quad_perm [1,0,3,2]
  else if constexpr (MASK == 2) return dpp_mov<0x4E>(v);   // quad_perm [2,3,0,1]
  else if constexpr (MASK == 8) return dpp_mov<0x128>(v);  // row_ror:8
  else return dpp_mov<0x1B>(dpp_mov<0x141>(v));            // xor7 o xor3
}
template <int MASK>
__device__ __forceinline__ v2f dpp2(v2f v) {
  v2f r; r.x = lane_xor<MASK>(v.x); r.y = lane_xor<MASK>(v.y); return r;
}

// --- Rot gates.  mA = (m00r, m00i, m01r, m01i);  m11=conj(m00), m10=-conj(m01)
template <int W>  // lane qubit, W in 0..3
__device__ __forceinline__ void rot_lane(v2f (&RE)[8], v2f (&IM)[8],
                                         const float4 mA, int g) {
  constexpr int LM = 1 << (3 - W);
  const unsigned bit = (g >> (3 - W)) & 1u;
  const int sgn = (int)(bit << 31);
  v2f Av = sp(mA.x);
  v2f Bv = sp(__int_as_float(__float_as_int(mA.y) ^ sgn));
  v2f Cv = sp(__int_as_float(__float_as_int(mA.z) ^ sgn));
  v2f Dv = sp(mA.w);
#pragma unroll
  for (int j = 0; j < 8; ++j) {
    v2f pr = dpp2<LM>(RE[j]);
    v2f pi = dpp2<LM>(IM[j]);
    v2f nr = pkfma(-Dv, pi, pkfma(Cv, pr, pkfma(-Bv, IM[j], Av * RE[j])));
    v2f ni = pkfma( Dv, pr, pkfma(Cv, pi, pkfma( Bv, RE[j], Av * IM[j])));
    RE[j] = nr; IM[j] = ni;
  }
}

template <int JM>  // reg qubit via j-bit: q4 JM=4, q5 JM=2, q6 JM=1
__device__ __forceinline__ void rot_regj(v2f (&RE)[8], v2f (&IM)[8],
                                         const float4 mA) {
  v2f M0r = sp(mA.x), M0i = sp(mA.y), M1r = sp(mA.z), M1i = sp(mA.w);
#pragma unroll
  for (int j = 0; j < 8; ++j) {
    if (!(j & JM)) {
      const int j1 = j | JM;
      v2f r0 = RE[j], i0 = IM[j], r1 = RE[j1], i1 = IM[j1];
      RE[j]  = pkfma(-M1i, i1, pkfma(M1r, r1, pkfma(-M0i, i0, M0r * r0)));
      IM[j]  = pkfma( M1i, r1, pkfma(M1r, i1, pkfma( M0i, r0, M0r * i0)));
      RE[j1] = pkfma( M0i, i1, pkfma(M0r, r1, pkfma(-M1i, i0, (-M1r) * r0)));
      IM[j1] = pkfma(-M0i, r1, pkfma(M0r, i1, pkfma( M1i, r0, (-M1r) * i0)));
    }
  }
}

__device__ __forceinline__ void rot_regh(v2f (&RE)[8], v2f (&IM)[8],
                                         const float4 mA) {  // q7 (h bit)
#pragma unroll
  for (int j = 0; j < 8; ++j) {
    float r0 = RE[j].x, i0 = IM[j].x, r1 = RE[j].y, i1 = IM[j].y;
    RE[j].x = fmaf(-mA.w, i1, fmaf(mA.z, r1, fmaf(-mA.y, i0, mA.x * r0)));
    IM[j].x = fmaf( mA.w, r1, fmaf(mA.z, i1, fmaf( mA.y, r0, mA.x * i0)));
    RE[j].y = fmaf( mA.y, i1, fmaf(mA.x, r1, fmaf(-mA.w, i0, -mA.z * r0)));
    IM[j].y = fmaf(-mA.y, r1, fmaf(mA.x, i1, fmaf( mA.w, r0, -mA.z * i0)));
  }
}

// --- CNOT with control+target both lane bits: single (masked) DPP per reg ---
// control g bit GPOS, target xor LM.
template <int GPOS, int LM>
__device__ __forceinline__ void cnot_LL(v2f (&RE)[8], v2f (&IM)[8], int g) {
  if constexpr (GPOS >= 2) {
    constexpr int BANK = (GPOS == 3) ? 0xC : 0xA;
    if constexpr (LM == 4) {  // xor4 = xor7 (full) then masked xor3
#pragma unroll
      for (int j = 0; j < 8; ++j) {
        float t0 = dpp_mov<0x141>(RE[j].x);
        float t1 = dpp_mov<0x141>(RE[j].y);
        float t2 = dpp_mov<0x141>(IM[j].x);
        float t3 = dpp_mov<0x141>(IM[j].y);
        RE[j].x = mdpp<0x1B, BANK>(RE[j].x, t0);
        RE[j].y = mdpp<0x1B, BANK>(RE[j].y, t1);
        IM[j].x = mdpp<0x1B, BANK>(IM[j].x, t2);
        IM[j].y = mdpp<0x1B, BANK>(IM[j].y, t3);
      }
    } else {
      constexpr int CTRL = (LM == 1) ? 0xB1 : (LM == 2) ? 0x4E : 0x128;
#pragma unroll
      for (int j = 0; j < 8; ++j) {
        RE[j].x = mdpp<CTRL, BANK>(RE[j].x, RE[j].x);
        RE[j].y = mdpp<CTRL, BANK>(RE[j].y, RE[j].y);
        IM[j].x = mdpp<CTRL, BANK>(IM[j].x, IM[j].x);
        IM[j].y = mdpp<CTRL, BANK>(IM[j].y, IM[j].y);
      }
    }
  } else {
    // control inside quad: the conditional swap IS a quad_perm
    constexpr int CTRL =
        (GPOS == 1 && LM == 1) ? 0xB4 :   // [0,1,3,2]
        (GPOS == 1 && LM == 2) ? 0x44 :   // [0,1,0,1]
        (GPOS == 0 && LM == 1) ? 0xA0 :   // [0,0,2,2]
                                 0x6C;    // GPOS==0, LM==2: [0,3,2,1]
#pragma unroll
    for (int j = 0; j < 8; ++j) {
      RE[j].x = dpp_mov<CTRL>(RE[j].x);
      RE[j].y = dpp_mov<CTRL>(RE[j].y);
      IM[j].x = dpp_mov<CTRL>(IM[j].x);
      IM[j].y = dpp_mov<CTRL>(IM[j].y);
    }
  }
}

template <int GPOS, int JM>  // C lane, T reg j-bit
__device__ __forceinline__ void cnot_LR(v2f (&RE)[8], v2f (&IM)[8], int g) {
  const bool cb = (g >> GPOS) & 1;
#pragma unroll
  for (int j = 0; j < 8; ++j) {
    if (!(j & JM)) {
      const int j1 = j | JM;
      v2f r0 = RE[j], r1 = RE[j1];
      RE[j] = cb ? r1 : r0;  RE[j1] = cb ? r0 : r1;
      v2f i0 = IM[j], i1 = IM[j1];
      IM[j] = cb ? i1 : i0;  IM[j1] = cb ? i0 : i1;
    }
  }
}
template <int GPOS>  // C lane, T h
__device__ __forceinline__ void cnot_LH(v2f (&RE)[8], v2f (&IM)[8], int g) {
  const bool cb = (g >> GPOS) & 1;
#pragma unroll
  for (int j = 0; j < 8; ++j) {
    v2f r = RE[j]; v2f rs; rs.x = r.y; rs.y = r.x;
    RE[j] = cb ? rs : r;
    v2f i = IM[j]; v2f is2; is2.x = i.y; is2.y = i.x;
    IM[j] = cb ? is2 : i;
  }
}
template <int JC, int LM>  // C reg j-bit, T lane
__device__ __forceinline__ void cnot_RL(v2f (&RE)[8], v2f (&IM)[8]) {
#pragma unroll
  for (int j = 0; j < 8; ++j) {
    if (j & JC) {
      RE[j] = dpp2<LM>(RE[j]);
      IM[j] = dpp2<LM>(IM[j]);
    }
  }
}
template <int JC>  // C reg j-bit, T h
__device__ __forceinline__ void cnot_RH(v2f (&RE)[8], v2f (&IM)[8]) {
#pragma unroll
  for (int j = 0; j < 8; ++j) {
    if (j & JC) {
      v2f r = RE[j]; RE[j].x = r.y; RE[j].y = r.x;
      v2f i = IM[j]; IM[j].x = i.y; IM[j].y = i.x;
    }
  }
}
template <int LM>  // C h, T lane (h=1 components move)
__device__ __forceinline__ void cnot_HL(v2f (&RE)[8], v2f (&IM)[8]) {
#pragma unroll
  for (int j = 0; j < 8; ++j) {
    RE[j].y = lane_xor<LM>(RE[j].y);
    IM[j].y = lane_xor<LM>(IM[j].y);
  }
}
template <int JC, int JT>  // C reg, T reg: static swaps (register renaming)
__device__ __forceinline__ void cnot_RR(v2f (&RE)[8], v2f (&IM)[8]) {
#pragma unroll
  for (int j = 0; j < 8; ++j) {
    if ((j & JC) && !(j & JT)) {
      const int j1 = j | JT;
      v2f t = RE[j]; RE[j] = RE[j1]; RE[j1] = t;
      t = IM[j]; IM[j] = IM[j1]; IM[j1] = t;
    }
  }
}

__device__ __forceinline__ void stage_fence() { __threadfence_block(); }

__global__ __launch_bounds__(256, 2) void hqc_kernel(
    const float* __restrict__ x,
    const float* __restrict__ w1, const float* __restrict__ b1,
    const float* __restrict__ w2, const float* __restrict__ b2,
    const float* __restrict__ w3, const float* __restrict__ b3,
    const float* __restrict__ qw,
    const float* __restrict__ wp1, const float* __restrict__ bp1,
    const float* __restrict__ wp2, const float* __restrict__ bp2,
    const float* __restrict__ wp3, const float* __restrict__ bp3,
    float* __restrict__ out, int B) {
  __shared__ __align__(16) float rotm[32][4];  // m00r,m00i,m01r,m01i per gate
  __shared__ float xbuf[16][44];
  __shared__ __align__(16) float hbuf[16][68];
  __shared__ float h2buf[16][34];
  __shared__ float qbuf[16][20];
  __shared__ float p1buf[16][34];
  __shared__ float p2buf[16][20];

  const int tid = threadIdx.x;
  const int g = tid & 15;
  const int ls = tid >> 4;
  const int s = blockIdx.x * 16 + ls;
  const bool valid = (s < B);

  // --- Rot coefficient setup: one thread per gate ---
  if (tid < 32) {
    float phi = qw[tid * 3 + 0];
    float th  = qw[tid * 3 + 1];
    float om  = qw[tid * 3 + 2];
    float st_, ct; sincosf(0.5f * th, &st_, &ct);
    float sa, ca;  sincosf(0.5f * (phi + om), &sa, &ca);
    float sb, cb;  sincosf(0.5f * (phi - om), &sb, &cb);
    rotm[tid][0] =  ca * ct;   // m00r
    rotm[tid][1] = -sa * ct;   // m00i
    rotm[tid][2] = -cb * st_;  // m01r
    rotm[tid][3] = -sb * st_;  // m01i
  }

  if (valid) {
    xbuf[ls][g]      = x[s * 41 + g];
    xbuf[ls][g + 16] = x[s * 41 + g + 16];
    if (g < 9) xbuf[ls][g + 32] = x[s * 41 + g + 32];
  }
  __syncthreads();

  // --- pre-MLP layer1: 41 -> 64 (packed) ---
  const float4* w1v = (const float4*)w1;  // [41][16]
  float4 bv = ((const float4*)b1)[g];
  v2f aA; aA.x = bv.x; aA.y = bv.y;
  v2f aB; aB.x = bv.z; aB.y = bv.w;
#pragma unroll 8
  for (int k = 0; k < 41; ++k) {
    float xk = xbuf[ls][k];
    float4 wv = w1v[k * 16 + g];
    v2f w01; w01.x = wv.x; w01.y = wv.y;
    v2f w23; w23.x = wv.z; w23.y = wv.w;
    v2f xv = sp(xk);
    aA = pkfma(xv, w01, aA);
    aB = pkfma(xv, w23, aB);
  }
  float4 st4;
  st4.x = fmaxf(aA.x, 0.f); st4.y = fmaxf(aA.y, 0.f);
  st4.z = fmaxf(aB.x, 0.f); st4.w = fmaxf(aB.y, 0.f);
  *(float4*)(&hbuf[ls][4 * g]) = st4;
  stage_fence();

  // --- layer2: 64 -> 32 (packed) ---
  const v2f* w2v = (const v2f*)w2;  // [64][16]
  v2f a2 = ((const v2f*)b2)[g];
#pragma unroll 8
  for (int k = 0; k < 64; ++k)
    a2 = pkfma(sp(hbuf[ls][k]), w2v[k * 16 + g], a2);
  h2buf[ls][2 * g]     = fmaxf(a2.x, 0.f);
  h2buf[ls][2 * g + 1] = fmaxf(a2.y, 0.f);
  stage_fence();

  // --- layer3: 32 -> 8, tanh, RY encoding ---
  if (g < 8) {
    float acc = b3[g];
#pragma unroll
    for (int k = 0; k < 32; ++k) acc = fmaf(h2buf[ls][k], w3[k * 8 + g], acc);
    float q = tanhf(acc);
    float sh, ch; sincosf(q * PI_HALF, &sh, &ch);
    qbuf[ls][g]     = ch;
    qbuf[ls][8 + g] = sh;
  }
  stage_fence();

  // --- init statevector ---
  float cwv[8], swv[8];
#pragma unroll
  for (int w = 0; w < 8; ++w) { cwv[w] = qbuf[ls][w]; swv[w] = qbuf[ls][8 + w]; }
  float lp = 1.0f;
#pragma unroll
  for (int w = 0; w < 4; ++w) lp *= ((g >> (3 - w)) & 1) ? swv[w] : cwv[w];
  float f45[4];
#pragma unroll
  for (int a = 0; a < 4; ++a)
    f45[a] = ((a & 2) ? swv[4] : cwv[4]) * ((a & 1) ? swv[5] : cwv[5]);
  v2f F67[2];
  F67[0].x = cwv[6] * cwv[7]; F67[0].y = cwv[6] * swv[7];
  F67[1].x = swv[6] * cwv[7]; F67[1].y = swv[6] * swv[7];
  v2f RE[8], IM[8];
#pragma unroll
  for (int j = 0; j < 8; ++j) {
    RE[j] = sp(lp * f45[j >> 1]) * F67[j & 1];
    IM[j] = sp(0.0f);
  }

#define RM(L, W) (*(const float4*)(&rotm[(L) * 8 + (W)][0]))
  // Prefetch the layer's 8 coefficient quads into registers (batched ds_reads,
  // keeps LDS latency off the gate-to-gate critical path).
#define ROTS(L)                                                          \
  {                                                                      \
    float4 c0 = RM(L, 0), c1 = RM(L, 1), c2 = RM(L, 2), c3 = RM(L, 3),   \
           c4 = RM(L, 4), c5 = RM(L, 5), c6 = RM(L, 6), c7 = RM(L, 7);   \
    rot_lane<0>(RE, IM, c0, g);                                          \
    rot_lane<1>(RE, IM, c1, g);                                          \
    rot_lane<2>(RE, IM, c2, g);                                          \
    rot_lane<3>(RE, IM, c3, g);                                          \
    rot_regj<4>(RE, IM, c4);                                             \
    rot_regj<2>(RE, IM, c5);                                             \
    rot_regj<1>(RE, IM, c6);                                             \
    rot_regh(RE, IM, c7);                                                \
  }

  // layer 0, r=1: (0,1)(1,2)(2,3)(3,4)(4,5)(5,6)(6,7)(7,0)
  ROTS(0)
  cnot_LL<3, 4>(RE, IM, g);  cnot_LL<2, 2>(RE, IM, g);
  cnot_LL<1, 1>(RE, IM, g);  cnot_LR<0, 4>(RE, IM, g);
  cnot_RR<4, 2>(RE, IM);     cnot_RR<2, 1>(RE, IM);
  cnot_RH<1>(RE, IM);        cnot_HL<8>(RE, IM);
  // layer 1, r=2: (0,2)(1,3)(2,4)(3,5)(4,6)(5,7)(6,0)(7,1)
  ROTS(1)
  cnot_LL<3, 2>(RE, IM, g);  cnot_LL<2, 1>(RE, IM, g);
  cnot_LR<1, 4>(RE, IM, g);  cnot_LR<0, 2>(RE, IM, g);
  cnot_RR<4, 1>(RE, IM);     cnot_RH<2>(RE, IM);
  cnot_RL<1, 8>(RE, IM);     cnot_HL<4>(RE, IM);
  // layer 2, r=3: (0,3)(1,4)(2,5)(3,6)(4,7)(5,0)(6,1)(7,2)
  ROTS(2)
  cnot_LL<3, 1>(RE, IM, g);  cnot_LR<2, 4>(RE, IM, g);
  cnot_LR<1, 2>(RE, IM, g);  cnot_LR<0, 1>(RE, IM, g);
  cnot_RH<4>(RE, IM);        cnot_RL<2, 8>(RE, IM);
  cnot_RL<1, 4>(RE, IM);     cnot_HL<2>(RE, IM);
  // layer 3, r=4: (0,4)(1,5)(2,6)(3,7)(4,0)(5,1)(6,2)(7,3)
  ROTS(3)
  cnot_LR<3, 4>(RE, IM, g);  cnot_LR<2, 2>(RE, IM, g);
  cnot_LR<1, 1>(RE, IM, g);  cnot_LH<0>(RE, IM, g);
  cnot_RL<4, 8>(RE, IM);     cnot_RL<2, 4>(RE, IM);
  cnot_RL<1, 2>(RE, IM);     cnot_HL<1>(RE, IM);

  // --- expectations ---
  v2f pv[8];
#pragma unroll
  for (int j = 0; j < 8; ++j) pv[j] = pkfma(RE[j], RE[j], IM[j] * IM[j]);
  v2f t01 = pv[0] + pv[1], t23 = pv[2] + pv[3];
  v2f t45 = pv[4] + pv[5], t67 = pv[6] + pv[7];
  v2f tlo = t01 + t23, thi = t45 + t67;
  v2f tv = tlo + thi;
  float tot = tv.x + tv.y;
  float s4 = thi.x + thi.y;                       // q4: j bit2
  v2f v5 = t23 + t67; float s5 = v5.x + v5.y;     // q5: j bit1
  v2f v6 = (pv[1] + pv[3]) + (pv[5] + pv[7]);
  float s6 = v6.x + v6.y;                         // q6: j bit0
  float s7 = tv.y;                                // q7: h
  float zp[8];
  zp[0] = ((g >> 3) & 1) ? -tot : tot;
  zp[1] = ((g >> 2) & 1) ? -tot : tot;
  zp[2] = ((g >> 1) & 1) ? -tot : tot;
  zp[3] = (g & 1) ? -tot : tot;
  zp[4] = fmaf(-2.f, s4, tot);
  zp[5] = fmaf(-2.f, s5, tot);
  zp[6] = fmaf(-2.f, s6, tot);
  zp[7] = fmaf(-2.f, s7, tot);
#pragma unroll
  for (int w = 0; w < 8; ++w) zp[w] += lane_xor<1>(zp[w]);
#pragma unroll
  for (int w = 0; w < 8; ++w) zp[w] += lane_xor<2>(zp[w]);
#pragma unroll
  for (int w = 0; w < 8; ++w) zp[w] += lane_xor<4>(zp[w]);
#pragma unroll
  for (int w = 0; w < 8; ++w) zp[w] += lane_xor<8>(zp[w]);

  // --- post-MLP layer1: 8 -> 32 (packed) ---
  const v2f* wp1v = (const v2f*)wp1;  // [8][16]
  v2f q1 = ((const v2f*)bp1)[g];
#pragma unroll
  for (int k = 0; k < 8; ++k)
    q1 = pkfma(sp(zp[k]), wp1v[k * 16 + g], q1);
  p1buf[ls][2 * g]     = fmaxf(q1.x, 0.f);
  p1buf[ls][2 * g + 1] = fmaxf(q1.y, 0.f);
  stage_fence();

  // --- post layer2: 32 -> 16 ---
  float q2 = bp2[g];
#pragma unroll
  for (int k = 0; k < 32; ++k) q2 = fmaf(p1buf[ls][k], wp2[k * 16 + g], q2);
  p2buf[ls][g] = fmaxf(q2, 0.f);
  stage_fence();

  // --- post layer3: 16 -> 5 ---
  if (g < 5 && valid) {
    float o = bp3[g];
#pragma unroll
    for (int k = 0; k < 16; ++k) o = fmaf(p2buf[ls][k], wp3[k * 5 + g], o);
    out[s * 5 + g] = o;
  }
}

extern "C" void kernel_launch(void* const* d_in, const int* in_sizes, int n_in,
                              void* d_out, int out_size, void* d_ws,
                              size_t ws_size, hipStream_t stream) {
  const float* x   = (const float*)d_in[0];
  const float* w1  = (const float*)d_in[1];
  const float* b1  = (const float*)d_in[2];
  const float* w2  = (const float*)d_in[3];
  const float* b2  = (const float*)d_in[4];
  const float* w3  = (const float*)d_in[5];
  const float* b3  = (const float*)d_in[6];
  const float* qw  = (const float*)d_in[7];
  const float* wp1 = (const float*)d_in[8];
  const float* bp1 = (const float*)d_in[9];
  const float* wp2 = (const float*)d_in[10];
  const float* bp2 = (const float*)d_in[11];
  const float* wp3 = (const float*)d_in[12];
  const float* bp3 = (const float*)d_in[13];
  float* out = (float*)d_out;
  const int B = in_sizes[0] / 41;
  const int blocks = (B + 15) / 16;
  hipLaunchKernelGGL(hqc_kernel, dim3(blocks), dim3(256), 0, stream,
                     x, w1, b1, w2, b2, w3, b3, qw,
                     wp1, bp1, wp2, bp2, wp3, bp3, out, B);
}